// Round 2
// baseline (3428.989 us; speedup 1.0000x reference)
//
#include <hip/hip_runtime.h>

#define WS    8
#define SHIFT 4
#define HH    256
#define WWID  256
#define DD    96
#define NH    6
#define DK    16
#define WS2   64
#define NTHR  384
#define LDP   (DD + 1)   // 97: odd stride -> 2-way (free) bank pattern
#define RPN   225        // (2*WS-1)^2

// region id along one axis for the Swin shift mask:
// rows 0..247 -> 0, 248..251 -> 1, 252..255 -> 2
__device__ __forceinline__ int region1d(int h) {
    return (h >= HH - SHIFT) ? 2 : ((h >= HH - WS) ? 1 : 0);
}

__global__ __launch_bounds__(NTHR)
void swin_attn_fused(const float* __restrict__ x,
                     const float* __restrict__ w_qkv,
                     const float* __restrict__ b_qkv,
                     const float* __restrict__ w_out,
                     const float* __restrict__ b_out,
                     const float* __restrict__ rpe_table,
                     float* __restrict__ out)
{
    // 48 KB arena: ks[NH][64][16] | vs[NH][64][16]; after attention the
    // arena is reused (overlay) as os[64][97] for the out-proj staging.
    __shared__ float kvbuf[2 * NH * WS2 * DK];
    __shared__ float rpe_s[NH][RPN];

    float (*ks)[WS2][DK] = (float (*)[WS2][DK])kvbuf;
    float (*vs)[WS2][DK] = (float (*)[WS2][DK])(kvbuf + NH * WS2 * DK);
    float (*os)[LDP]     = (float (*)[LDP])kvbuf;          // overlay, used post-barrier

    const int blk = blockIdx.x;
    const int b   = blk >> 10;
    const int wi  = (blk >> 5) & 31;
    const int wj  = blk & 31;

    const int tid = threadIdx.x;
    const int p   = tid & 63;       // window position = qr*8+qc
    const int hg  = tid >> 6;       // head (= wave id)

    // stage rpe table (head-major) into LDS
    for (int idx = tid; idx < NH * RPN; idx += NTHR) {
        int h = idx / RPN;
        int r = idx - h * RPN;
        rpe_s[h][r] = rpe_table[r * NH + h];
    }

    const int qr = p >> 3, qc = p & 7;
    const int gh = (wi * WS + qr + SHIFT) & (HH - 1);
    const int gw = (wj * WS + qc + SHIFT) & (WWID - 1);
    const size_t rowoff = ((size_t)b * HH + gh) * WWID + gw;
    const float* xrow = x + rowoff * DD;

    // ---- Phase 1: qkv projection; x read direct from global (L1-resident) ----
    float accq[DK], acck[DK], accv[DK];
    #pragma unroll
    for (int d = 0; d < DK; ++d) {
        accq[d] = b_qkv[hg * DK + d];
        acck[d] = b_qkv[DD + hg * DK + d];
        accv[d] = b_qkv[2 * DD + hg * DK + d];
    }
    #pragma unroll
    for (int kc = 0; kc < DD; kc += 32) {
        float xchunk[32];
        #pragma unroll
        for (int i = 0; i < 8; ++i) {
            float4 t = *reinterpret_cast<const float4*>(xrow + kc + 4 * i);
            xchunk[4 * i + 0] = t.x; xchunk[4 * i + 1] = t.y;
            xchunk[4 * i + 2] = t.z; xchunk[4 * i + 3] = t.w;
        }
        #pragma unroll
        for (int kk = 0; kk < 32; ++kk) {
            float xv = xchunk[kk];
            const float* wr = w_qkv + (size_t)(kc + kk) * (3 * DD) + hg * DK;
            #pragma unroll
            for (int d = 0; d < DK; ++d) accq[d] = fmaf(xv, wr[d], accq[d]);
            #pragma unroll
            for (int d = 0; d < DK; ++d) acck[d] = fmaf(xv, wr[DD + d], acck[d]);
            #pragma unroll
            for (int d = 0; d < DK; ++d) accv[d] = fmaf(xv, wr[2 * DD + d], accv[d]);
        }
    }
    float qreg[DK];
    #pragma unroll
    for (int d = 0; d < DK; ++d) qreg[d] = accq[d] * 0.25f;   // fold 1/sqrt(dk)
    #pragma unroll
    for (int d = 0; d < DK; ++d) ks[hg][p][d] = acck[d];
    #pragma unroll
    for (int d = 0; d < DK; ++d) vs[hg][p][d] = accv[d];
    __syncthreads();

    // ---- Phase 2: attention. Wave hg = head, lane p = query row ----
    const int reg_q = region1d(wi * WS + qr) * 3 + region1d(wj * WS + qc);
    int reg_r[WS], reg_c[WS];
    #pragma unroll
    for (int i = 0; i < WS; ++i) {
        reg_r[i] = region1d(wi * WS + i) * 3;
        reg_c[i] = region1d(wj * WS + i);
    }

    float sc[WS2];
    float mx = -3.0e38f;
    #pragma unroll
    for (int kp = 0; kp < WS2; ++kp) {
        const int kr = kp >> 3, kc2 = kp & 7;
        // wave-uniform aligned b128 broadcast reads of the k-row
        const float4* krow = reinterpret_cast<const float4*>(&ks[hg][kp][0]);
        float4 k0 = krow[0], k1 = krow[1], k2 = krow[2], k3 = krow[3];
        float s;
        s  = qreg[0] * k0.x + qreg[1] * k0.y + qreg[2] * k0.z + qreg[3] * k0.w;
        s += qreg[4] * k1.x + qreg[5] * k1.y + qreg[6] * k1.z + qreg[7] * k1.w;
        s += qreg[8] * k2.x + qreg[9] * k2.y + qreg[10] * k2.z + qreg[11] * k2.w;
        s += qreg[12] * k3.x + qreg[13] * k3.y + qreg[14] * k3.z + qreg[15] * k3.w;
        const int ridx = (qr - kr + 7) * 15 + (qc - kc2 + 7);
        s += rpe_s[hg][ridx];
        if (reg_r[kr] + reg_c[kc2] != reg_q) s = -1e9f;
        sc[kp] = s;
        mx = fmaxf(mx, s);
    }
    float ssum = 0.f;
    #pragma unroll
    for (int kp = 0; kp < WS2; ++kp) {
        float e = __expf(sc[kp] - mx);
        sc[kp] = e;
        ssum += e;
    }
    const float rinv = 1.0f / ssum;

    float o[DK];
    #pragma unroll
    for (int d = 0; d < DK; ++d) o[d] = 0.f;
    #pragma unroll
    for (int kp = 0; kp < WS2; ++kp) {
        const float a = sc[kp] * rinv;
        const float4* vrow = reinterpret_cast<const float4*>(&vs[hg][kp][0]);
        float4 v0 = vrow[0], v1 = vrow[1], v2 = vrow[2], v3 = vrow[3];
        o[0]  = fmaf(a, v0.x, o[0]);  o[1]  = fmaf(a, v0.y, o[1]);
        o[2]  = fmaf(a, v0.z, o[2]);  o[3]  = fmaf(a, v0.w, o[3]);
        o[4]  = fmaf(a, v1.x, o[4]);  o[5]  = fmaf(a, v1.y, o[5]);
        o[6]  = fmaf(a, v1.z, o[6]);  o[7]  = fmaf(a, v1.w, o[7]);
        o[8]  = fmaf(a, v2.x, o[8]);  o[9]  = fmaf(a, v2.y, o[9]);
        o[10] = fmaf(a, v2.z, o[10]); o[11] = fmaf(a, v2.w, o[11]);
        o[12] = fmaf(a, v3.x, o[12]); o[13] = fmaf(a, v3.y, o[13]);
        o[14] = fmaf(a, v3.z, o[14]); o[15] = fmaf(a, v3.w, o[15]);
    }
    __syncthreads();   // all waves done reading ks/vs -> overlay becomes legal

    #pragma unroll
    for (int d = 0; d < DK; ++d) os[p][hg * DK + d] = o[d];
    __syncthreads();

    // ---- Phase 3: output projection ----
    float acc[DK];
    #pragma unroll
    for (int d = 0; d < DK; ++d) acc[d] = b_out[hg * DK + d];
    #pragma unroll
    for (int k = 0; k < DD; ++k) {
        const float a = os[p][k];        // stride 97 -> 2-way (free)
        const float* wr = w_out + (size_t)k * DD + hg * DK;
        #pragma unroll
        for (int d = 0; d < DK; ++d) acc[d] = fmaf(a, wr[d], acc[d]);
    }
    float* orow = out + rowoff * DD + hg * DK;
    float4* o4 = reinterpret_cast<float4*>(orow);
    o4[0] = make_float4(acc[0],  acc[1],  acc[2],  acc[3]);
    o4[1] = make_float4(acc[4],  acc[5],  acc[6],  acc[7]);
    o4[2] = make_float4(acc[8],  acc[9],  acc[10], acc[11]);
    o4[3] = make_float4(acc[12], acc[13], acc[14], acc[15]);
}

extern "C" void kernel_launch(void* const* d_in, const int* in_sizes, int n_in,
                              void* d_out, int out_size, void* d_ws, size_t ws_size,
                              hipStream_t stream) {
    const float* x    = (const float*)d_in[0];
    const float* wqkv = (const float*)d_in[1];
    const float* bqkv = (const float*)d_in[2];
    const float* wout = (const float*)d_in[3];
    const float* bout = (const float*)d_in[4];
    const float* rpe  = (const float*)d_in[5];
    // d_in[6] (rp_index) and d_in[7] (mask) are recomputed in-kernel.
    float* out = (float*)d_out;

    const int B = in_sizes[0] / (HH * WWID * DD);
    dim3 grid(B * 32 * 32);
    dim3 block(NTHR);
    hipLaunchKernelGGL(swin_attn_fused, grid, block, 0, stream,
                       x, wqkv, bqkv, wout, bout, rpe, out);
}

// Round 3
// 459.373 us; speedup vs baseline: 7.4645x; 7.4645x over previous
//
#include <hip/hip_runtime.h>
#include <stdint.h>

#define HH    256
#define DD    96
#define NH    6
#define WSZ   8

typedef __bf16 bf16_t;
typedef bf16_t bf16x8 __attribute__((ext_vector_type(8)));
typedef float  f32x4  __attribute__((ext_vector_type(4)));

union U4 { bf16x8 v; uint32_t u[4]; };
union U2 { bf16_t h[2]; uint32_t u; };

static __device__ __forceinline__ uint32_t pack2(float a, float b) {
    U2 x; x.h[0] = (bf16_t)a; x.h[1] = (bf16_t)b; return x.u;
}

// ---- workspace layout (bytes) ----
#define OFF_WQ_HI 0        // 18*3*64*8 bf16 = 55296 B
#define OFF_WQ_LO 55296
#define OFF_WO_HI 110592   // 6*3*64*8 bf16 = 18432 B
#define OFF_WO_LO 129024
#define OFF_RPE   147456   // 6*64*64 f32 = 98304 B
// total 245760 B

// ---- LDS layout (bytes) ----
#define L_XS_HI 0          // [64][96] bf16 = 12288
#define L_XS_LO 12288
#define L_QS    24576      // [6][64][16] bf16 = 12288
#define L_KS    36864      // [6][64][16] bf16 = 12288
#define L_VT    49152      // [6][16][72] bf16 = 13824
#define LDS_BYTES 62976
// o_hi/o_lo overlay xs_hi/xs_lo after the post-proj barrier

__global__ __launch_bounds__(256)
void prep_kernel(const float* __restrict__ wqkv, const float* __restrict__ wout,
                 const float* __restrict__ rpe, char* __restrict__ ws)
{
    bf16_t* wq_hi = (bf16_t*)(ws + OFF_WQ_HI);
    bf16_t* wq_lo = (bf16_t*)(ws + OFF_WQ_LO);
    bf16_t* wo_hi = (bf16_t*)(ws + OFF_WO_HI);
    bf16_t* wo_lo = (bf16_t*)(ws + OFF_WO_LO);
    float*  rpe_b = (float*)(ws + OFF_RPE);

    int idx = blockIdx.x * 256 + threadIdx.x;
    // w_qkv fragments: [nt<18][ks<3][lane][8]
    if (idx < 27648) {
        int j = idx & 7, lane = (idx >> 3) & 63, rest = idx >> 9;
        int ks = rest % 3, nt = rest / 3;
        int k = ks * 32 + ((lane >> 4) << 3) + j;
        int n = nt * 16 + (lane & 15);
        float v = wqkv[k * 288 + n];
        bf16_t h = (bf16_t)v;
        wq_hi[idx] = h;
        wq_lo[idx] = (bf16_t)(v - (float)h);
    }
    // w_out fragments: [nt<6][ks<3][lane][8]
    if (idx < 9216) {
        int j = idx & 7, lane = (idx >> 3) & 63, rest = idx >> 9;
        int ks = rest % 3, nt = rest / 3;
        int k = ks * 32 + ((lane >> 4) << 3) + j;
        int n = nt * 16 + (lane & 15);
        float v = wout[k * 96 + n];
        bf16_t h = (bf16_t)v;
        wo_hi[idx] = h;
        wo_lo[idx] = (bf16_t)(v - (float)h);
    }
    // expanded rpe bias: [h][k][q]
    if (idx < 24576) {
        int h = idx >> 12, r = idx & 4095, k = r >> 6, q = r & 63;
        int qr = q >> 3, qc = q & 7, kr = k >> 3, kc = k & 7;
        rpe_b[idx] = rpe[((qr - kr + 7) * 15 + (qc - kc + 7)) * NH + h];
    }
}

__global__ __launch_bounds__(384, 2)
void swin_mfma(const float* __restrict__ x,
               const float* __restrict__ b_qkv,
               const float* __restrict__ b_out,
               const char*  __restrict__ ws,
               float* __restrict__ out)
{
    extern __shared__ char smem[];
    bf16_t* xs_hi = (bf16_t*)(smem + L_XS_HI);
    bf16_t* xs_lo = (bf16_t*)(smem + L_XS_LO);
    bf16_t* qs    = (bf16_t*)(smem + L_QS);
    bf16_t* ks_l  = (bf16_t*)(smem + L_KS);
    bf16_t* vt    = (bf16_t*)(smem + L_VT);
    bf16_t* o_hi  = xs_hi;   // overlay (post-barrier)
    bf16_t* o_lo  = xs_lo;

    const bf16_t* wq_hi = (const bf16_t*)(ws + OFF_WQ_HI);
    const bf16_t* wq_lo = (const bf16_t*)(ws + OFF_WQ_LO);
    const bf16_t* wo_hi = (const bf16_t*)(ws + OFF_WO_HI);
    const bf16_t* wo_lo = (const bf16_t*)(ws + OFF_WO_LO);
    const float*  rpe_b = (const float*)(ws + OFF_RPE);

    const int blk = blockIdx.x;
    const int b   = blk >> 10;
    const int wi  = (blk >> 5) & 31;
    const int wj  = blk & 31;

    const int tid  = threadIdx.x;
    const int lane = tid & 63;
    const int w    = tid >> 6;      // wave = head
    const int g    = lane >> 4;     // lane group 0..3
    const int c    = lane & 15;

    const f32x4 zf = {0.f, 0.f, 0.f, 0.f};

    // ---- Phase 0: stage x -> xs_hi/xs_lo (shifted gather) ----
    #pragma unroll
    for (int it = 0; it < 4; ++it) {
        int f4  = tid + it * 384;          // float4 index over [64][24]
        int row = f4 / 24, c4 = f4 - row * 24;
        int r = row >> 3, cl = row & 7;
        int gh = (wi * WSZ + r + 4) & 255;
        int gw = (wj * WSZ + cl + 4) & 255;
        const float4 v = *(const float4*)(x + (((size_t)b * HH + gh) * HH + gw) * DD + c4 * 4);
        float f0 = v.x, f1 = v.y, f2 = v.z, f3 = v.w;
        bf16_t h0 = (bf16_t)f0, h1 = (bf16_t)f1, h2 = (bf16_t)f2, h3 = (bf16_t)f3;
        uint2 hv, lv;
        hv.x = pack2(f0, f1); hv.y = pack2(f2, f3);
        lv.x = pack2(f0 - (float)h0, f1 - (float)h1);
        lv.y = pack2(f2 - (float)h2, f3 - (float)h3);
        *(uint2*)&xs_hi[row * 96 + c4 * 4] = hv;
        *(uint2*)&xs_lo[row * 96 + c4 * 4] = lv;
    }
    __syncthreads();

    // ---- Phase 1: QKV projection (split-bf16, 3-term). Wave w owns n-tiles {w, 6+w, 12+w} ----
    f32x4 acc[3][4];
    #pragma unroll
    for (int t = 0; t < 3; ++t) {
        float bias = b_qkv[t * 96 + w * 16 + c];
        #pragma unroll
        for (int mt = 0; mt < 4; ++mt) acc[t][mt] = (f32x4){bias, bias, bias, bias};
    }
    #pragma unroll
    for (int ks = 0; ks < 3; ++ks) {
        bf16x8 ah[4], al[4];
        #pragma unroll
        for (int mt = 0; mt < 4; ++mt) {
            ah[mt] = *(const bf16x8*)&xs_hi[(mt * 16 + c) * 96 + ks * 32 + g * 8];
            al[mt] = *(const bf16x8*)&xs_lo[(mt * 16 + c) * 96 + ks * 32 + g * 8];
        }
        #pragma unroll
        for (int t = 0; t < 3; ++t) {
            int nt = t * 6 + w;
            const bf16x8 bh = *(const bf16x8*)&wq_hi[((nt * 3 + ks) * 64 + lane) * 8];
            const bf16x8 bl = *(const bf16x8*)&wq_lo[((nt * 3 + ks) * 64 + lane) * 8];
            #pragma unroll
            for (int mt = 0; mt < 4; ++mt) {
                acc[t][mt] = __builtin_amdgcn_mfma_f32_16x16x32_bf16(ah[mt], bh, acc[t][mt], 0, 0, 0);
                acc[t][mt] = __builtin_amdgcn_mfma_f32_16x16x32_bf16(ah[mt], bl, acc[t][mt], 0, 0, 0);
                acc[t][mt] = __builtin_amdgcn_mfma_f32_16x16x32_bf16(al[mt], bh, acc[t][mt], 0, 0, 0);
            }
        }
    }
    // write Q (x0.25), K, V^T for head w
    #pragma unroll
    for (int mt = 0; mt < 4; ++mt) {
        #pragma unroll
        for (int i = 0; i < 4; ++i) {
            int row = mt * 16 + g * 4 + i;
            qs[w * 1024 + row * 16 + c]   = (bf16_t)(acc[0][mt][i] * 0.25f);
            ks_l[w * 1024 + row * 16 + c] = (bf16_t)acc[1][mt][i];
            vt[w * 1152 + c * 72 + row]   = (bf16_t)acc[2][mt][i];
        }
    }
    __syncthreads();   // all proj reads of xs done -> o overlay becomes legal

    // ---- Phase 2: attention for head w (S^T = K @ Q^T, K-dim 16 zero-padded to 32) ----
    U4 z4; z4.u[0] = z4.u[1] = z4.u[2] = z4.u[3] = 0;
    bf16x8 ak[4], bq[4];
    #pragma unroll
    for (int kt = 0; kt < 4; ++kt) {
        U4 t = z4;
        if (g < 2) t.v = *(const bf16x8*)&ks_l[w * 1024 + (kt * 16 + c) * 16 + g * 8];
        ak[kt] = t.v;
    }
    #pragma unroll
    for (int nt = 0; nt < 4; ++nt) {
        U4 t = z4;
        if (g < 2) t.v = *(const bf16x8*)&qs[w * 1024 + (nt * 16 + c) * 16 + g * 8];
        bq[nt] = t.v;
    }
    f32x4 st[4][4];
    #pragma unroll
    for (int kt = 0; kt < 4; ++kt)
        #pragma unroll
        for (int nt = 0; nt < 4; ++nt)
            st[kt][nt] = __builtin_amdgcn_mfma_f32_16x16x32_bf16(ak[kt], bq[nt], zf, 0, 0, 0);

    // rpe + mask + softmax (per lane: 4 q's x 16 k's; row-reduce over 4 lanes)
    const float* rpe_w = rpe_b + w * 4096;
    const int e_wi = (wi == 31), e_wj = (wj == 31);
    const bool edge = e_wi || e_wj;
    int rk[4][4];
    #pragma unroll
    for (int kt = 0; kt < 4; ++kt)
        #pragma unroll
        for (int i = 0; i < 4; ++i) {
            int k = kt * 16 + g * 4 + i;
            int kr = k >> 3, kc = k & 7;
            rk[kt][i] = (e_wi ? (kr >= 4 ? 2 : 1) : 0) * 3 + (e_wj ? (kc >= 4 ? 2 : 1) : 0);
        }

    uint32_t pk[4][4][2];
    #pragma unroll
    for (int nt = 0; nt < 4; ++nt) {
        int q = nt * 16 + c, qr = q >> 3, qc = q & 7;
        int rq = (e_wi ? (qr >= 4 ? 2 : 1) : 0) * 3 + (e_wj ? (qc >= 4 ? 2 : 1) : 0);
        float sv[16];
        float m = -3.0e38f;
        #pragma unroll
        for (int kt = 0; kt < 4; ++kt)
            #pragma unroll
            for (int i = 0; i < 4; ++i) {
                float s = st[kt][nt][i] + rpe_w[(kt * 16 + g * 4 + i) * 64 + q];
                if (edge && (rk[kt][i] != rq)) s = -1e9f;
                sv[kt * 4 + i] = s;
                m = fmaxf(m, s);
            }
        m = fmaxf(m, __shfl_xor(m, 16));
        m = fmaxf(m, __shfl_xor(m, 32));
        float sum = 0.f;
        #pragma unroll
        for (int e = 0; e < 16; ++e) { sv[e] = __expf(sv[e] - m); sum += sv[e]; }
        sum += __shfl_xor(sum, 16);
        sum += __shfl_xor(sum, 32);
        float rinv = 1.0f / sum;
        #pragma unroll
        for (int kt = 0; kt < 4; ++kt) {
            pk[nt][kt][0] = pack2(sv[kt * 4 + 0] * rinv, sv[kt * 4 + 1] * rinv);
            pk[nt][kt][1] = pack2(sv[kt * 4 + 2] * rinv, sv[kt * 4 + 3] * rinv);
        }
    }

    // PV: O = P @ V, A-frags assembled via shuffles from register P
    f32x4 oacc[4];
    #pragma unroll
    for (int mt = 0; mt < 4; ++mt) oacc[mt] = zf;
    #pragma unroll
    for (int ks = 0; ks < 2; ++ks) {
        const bf16x8 bv = *(const bf16x8*)&vt[w * 1152 + c * 72 + ks * 32 + g * 8];
        #pragma unroll
        for (int mt = 0; mt < 4; ++mt) {
            U4 af;
            #pragma unroll
            for (int jj = 0; jj < 4; ++jj) {
                int srcg = ((g & 1) << 1) + (jj >> 1);
                int src  = (srcg << 4) + c;
                uint32_t v0 = (uint32_t)__shfl((int)pk[mt][ks * 2 + 0][jj & 1], src);
                uint32_t v1 = (uint32_t)__shfl((int)pk[mt][ks * 2 + 1][jj & 1], src);
                af.u[jj] = (g >= 2) ? v1 : v0;
            }
            oacc[mt] = __builtin_amdgcn_mfma_f32_16x16x32_bf16(af.v, bv, oacc[mt], 0, 0, 0);
        }
    }
    // write attention output (split) into overlay
    #pragma unroll
    for (int mt = 0; mt < 4; ++mt)
        #pragma unroll
        for (int i = 0; i < 4; ++i) {
            int row = mt * 16 + g * 4 + i;
            float f = oacc[mt][i];
            bf16_t h = (bf16_t)f;
            o_hi[row * 96 + w * 16 + c] = h;
            o_lo[row * 96 + w * 16 + c] = (bf16_t)(f - (float)h);
        }
    __syncthreads();

    // ---- Phase 3: out-projection (split-bf16, 3-term). Wave w -> cols [w*16, w*16+16) ----
    f32x4 acc3[4];
    {
        float bo = b_out[w * 16 + c];
        #pragma unroll
        for (int mt = 0; mt < 4; ++mt) acc3[mt] = (f32x4){bo, bo, bo, bo};
    }
    #pragma unroll
    for (int ks = 0; ks < 3; ++ks) {
        bf16x8 ah[4], al[4];
        #pragma unroll
        for (int mt = 0; mt < 4; ++mt) {
            ah[mt] = *(const bf16x8*)&o_hi[(mt * 16 + c) * 96 + ks * 32 + g * 8];
            al[mt] = *(const bf16x8*)&o_lo[(mt * 16 + c) * 96 + ks * 32 + g * 8];
        }
        const bf16x8 bh = *(const bf16x8*)&wo_hi[((w * 3 + ks) * 64 + lane) * 8];
        const bf16x8 bl = *(const bf16x8*)&wo_lo[((w * 3 + ks) * 64 + lane) * 8];
        #pragma unroll
        for (int mt = 0; mt < 4; ++mt) {
            acc3[mt] = __builtin_amdgcn_mfma_f32_16x16x32_bf16(ah[mt], bh, acc3[mt], 0, 0, 0);
            acc3[mt] = __builtin_amdgcn_mfma_f32_16x16x32_bf16(ah[mt], bl, acc3[mt], 0, 0, 0);
            acc3[mt] = __builtin_amdgcn_mfma_f32_16x16x32_bf16(al[mt], bh, acc3[mt], 0, 0, 0);
        }
    }
    // store (shifted scatter)
    #pragma unroll
    for (int mt = 0; mt < 4; ++mt)
        #pragma unroll
        for (int i = 0; i < 4; ++i) {
            int row = mt * 16 + g * 4 + i;
            int r = row >> 3, cl = row & 7;
            int gh = (wi * WSZ + r + 4) & 255;
            int gw = (wj * WSZ + cl + 4) & 255;
            out[(((size_t)b * HH + gh) * HH + gw) * DD + w * 16 + c] = acc3[mt][i];
        }
}

extern "C" void kernel_launch(void* const* d_in, const int* in_sizes, int n_in,
                              void* d_out, int out_size, void* d_ws, size_t ws_size,
                              hipStream_t stream) {
    const float* x    = (const float*)d_in[0];
    const float* wqkv = (const float*)d_in[1];
    const float* bqkv = (const float*)d_in[2];
    const float* wout = (const float*)d_in[3];
    const float* bout = (const float*)d_in[4];
    const float* rpe  = (const float*)d_in[5];
    float* out = (float*)d_out;
    char* ws = (char*)d_ws;

    const int B = in_sizes[0] / (HH * HH * DD);

    hipLaunchKernelGGL(prep_kernel, dim3(108), dim3(256), 0, stream, wqkv, wout, rpe, ws);
    hipLaunchKernelGGL(swin_mfma, dim3(B * 1024), dim3(384), LDS_BYTES, stream,
                       x, bqkv, bout, (const char*)ws, out);
}